// Round 2
// baseline (1040.666 us; speedup 1.0000x reference)
//
#include <hip/hip_runtime.h>
#include <cstdint>
#include <cstddef>

// Problem constants (fixed by the reference)
#define B_ROWS 8192
#define E_EXP  8

typedef unsigned short ushort_t;
typedef short bf16x8 __attribute__((ext_vector_type(8)));
typedef float f32x4  __attribute__((ext_vector_type(4)));

__device__ __forceinline__ ushort_t f2b(float f) {
  union { float f; unsigned int i; } v; v.f = f;
  unsigned int u = v.i;
  unsigned int r = (u + 0x7fffu + ((u >> 16) & 1u)) >> 16;
  return (ushort_t)r;
}
__device__ __forceinline__ float eluf(float x) {
  return x > 0.f ? x : (__expf(x) - 1.f);
}

// ---------------------------------------------------------------------------
// Weight transpose + fp32->bf16: w flat [R][C] -> wT [C][R] bf16.
// ---------------------------------------------------------------------------
__global__ void transpose_k(const float* __restrict__ src,
                            ushort_t* __restrict__ dst, int R, int C) {
  __shared__ ushort_t tile[64][65];
  int c0 = blockIdx.x * 64, r0 = blockIdx.y * 64;
  int x = threadIdx.x, y = threadIdx.y;
#pragma unroll
  for (int i = 0; i < 4; ++i)
    tile[y + 16 * i][x] = f2b(src[(size_t)(r0 + y + 16 * i) * C + c0 + x]);
  __syncthreads();
#pragma unroll
  for (int i = 0; i < 4; ++i)
    dst[(size_t)(c0 + y + 16 * i) * R + r0 + x] = tile[x][y + 16 * i];
}

// ---------------------------------------------------------------------------
// Gating MLP (pure fp32). Emits:
//   coeff[b][e]  softmax probs
//   rat1[b][e]   full-chain Horner scales (e<7: c_e/c_{e+1}; e=7: c_7)
//   rat2[b][e]   2-way split {0-3},{4-7}: e in {3,7}: c_e; else ratio
// ---------------------------------------------------------------------------
__global__ __launch_bounds__(128) void gate_k(
    const float* __restrict__ z, const float* __restrict__ c,
    const float* __restrict__ g0w, const float* __restrict__ g0b,
    const float* __restrict__ g1w, const float* __restrict__ g1b,
    const float* __restrict__ g2w, const float* __restrict__ g2b,
    float* __restrict__ coeff, float* __restrict__ rat1,
    float* __restrict__ rat2) {
  __shared__ float xs[4][320];
  __shared__ float h1[4][128];
  __shared__ float h2[4][128];
  __shared__ float lg[4][8];
  __shared__ float pr[4][8];
  int t = threadIdx.x;
  int r0 = blockIdx.x * 4;
  for (int idx = t; idx < 4 * 320; idx += 128) {
    int r = idx / 320, j = idx % 320;
    xs[r][j] = (j < 64) ? z[(size_t)(r0 + r) * 64 + j]
                        : c[(size_t)(r0 + r) * 256 + j - 64];
  }
  __syncthreads();
  {
    float bb = g0b[t];
    float a0 = bb, a1 = bb, a2 = bb, a3 = bb;
    for (int j = 0; j < 320; ++j) {
      float wv = g0w[j * 128 + t];
      a0 += xs[0][j] * wv; a1 += xs[1][j] * wv;
      a2 += xs[2][j] * wv; a3 += xs[3][j] * wv;
    }
    h1[0][t] = eluf(a0); h1[1][t] = eluf(a1);
    h1[2][t] = eluf(a2); h1[3][t] = eluf(a3);
  }
  __syncthreads();
  {
    float bb = g1b[t];
    float a0 = bb, a1 = bb, a2 = bb, a3 = bb;
    for (int j = 0; j < 128; ++j) {
      float wv = g1w[j * 128 + t];
      a0 += h1[0][j] * wv; a1 += h1[1][j] * wv;
      a2 += h1[2][j] * wv; a3 += h1[3][j] * wv;
    }
    h2[0][t] = eluf(a0); h2[1][t] = eluf(a1);
    h2[2][t] = eluf(a2); h2[3][t] = eluf(a3);
  }
  __syncthreads();
  if (t < 32) {
    int r = t >> 3, e = t & 7;
    float a = g2b[e];
    for (int j = 0; j < 128; ++j) a += h2[r][j] * g2w[j * 8 + e];
    lg[r][e] = a;
  }
  __syncthreads();
  if (t < 32) {
    int r = t >> 3, e = t & 7;
    float mx = lg[r][0];
#pragma unroll
    for (int i = 1; i < 8; ++i) mx = fmaxf(mx, lg[r][i]);
    float s = 0.f;
#pragma unroll
    for (int i = 0; i < 8; ++i) s += __expf(lg[r][i] - mx);
    float p = __expf(lg[r][e] - mx) / s;
    coeff[(size_t)(r0 + r) * 8 + e] = p;
    pr[r][e] = p;
  }
  __syncthreads();
  if (t < 32) {
    int r = t >> 3, e = t & 7;
    float pe = pr[r][e];
    float ratio = (e < 7) ? pe / fmaxf(pr[r][e + 1], 1e-30f) : pe;
    rat1[(size_t)(r0 + r) * 8 + e] = ratio;
    rat2[(size_t)(r0 + r) * 8 + e] = (e == 3 || e == 7) ? pe : ratio;
  }
}

// ---------------------------------------------------------------------------
// LayerNorm over concat([z_row, prev_row]) -> out [B][J] bf16.
//   cf != null : prev = elu(p0 + sum_e cf[row,e]*bias[e,:])  (post-GEMM layers)
//   cf == null : prev = p0 raw (layer-0 path reading c)
// ---------------------------------------------------------------------------
__global__ __launch_bounds__(128) void ln_concat_k(
    const float* __restrict__ z, const float* __restrict__ p0,
    const float* __restrict__ cf, const float* __restrict__ bias,
    ushort_t* __restrict__ out, int Pw, int J) {
  int row = blockIdx.x, t = threadIdx.x;
  float vals[9];
  int n = (J + 127) >> 7;
  float cr[8];
  if (cf) {
#pragma unroll
    for (int e = 0; e < 8; ++e) cr[e] = cf[(size_t)row * 8 + e];
  }
  float s = 0.f, s2 = 0.f;
  for (int k = 0; k < n; ++k) {
    int i = t + (k << 7);
    float x = 0.f;
    if (i < J) {
      if (i < 64) {
        x = z[(size_t)row * 64 + i];
      } else if (cf) {
        int j = i - 64;
        float v = p0[(size_t)row * Pw + j];
#pragma unroll
        for (int e = 0; e < 8; ++e) v += cr[e] * bias[(size_t)e * Pw + j];
        x = eluf(v);
      } else {
        x = p0[(size_t)row * Pw + i - 64];
      }
    }
    vals[k] = x; s += x; s2 += x * x;
  }
  for (int off = 32; off > 0; off >>= 1) {
    s += __shfl_down(s, off);
    s2 += __shfl_down(s2, off);
  }
  __shared__ float red[4];
  int wid = t >> 6, lane = t & 63;
  if (lane == 0) { red[wid * 2] = s; red[wid * 2 + 1] = s2; }
  __syncthreads();
  float S = red[0] + red[2], S2 = red[1] + red[3];
  float inv = 1.f / (float)J;
  float m = S * inv;
  float var = S2 * inv - m * m;
  float rstd = rsqrtf(var + 1e-5f);
  for (int k = 0; k < n; ++k) {
    int i = t + (k << 7);
    if (i < J) out[(size_t)row * J + i] = f2b((vals[k] - m) * rstd);
  }
}

// ---------------------------------------------------------------------------
// Fused MoE GEMM, round 8: 2-phase double-buffered pipeline (T3-minimum).
//
// Round-7 post-mortem: occupancy 22.7->36.4% with ZERO speedup. The limit is
// the per-block critical path: {stage -> full vmcnt(0) drain -> compute} eats
// an L3-latency drain per K-step (W streams 17.8MB/XCD, misses L2). Fix per
// the measured 2-phase recipe: issue NEXT tile's global_load_lds BEFORE
// computing current tile; the barrier drain then overlaps with compute.
//
// 256x128 block tile, 512 thr / 8 waves (4Mx2N, per-wave 64x64), BK=64,
// LDS: A 2x32KB dbuf + W 2x16KB dbuf + scales 9KB = 105KB -> 1 block/CU
// (by design: pipeline hides latency in-block, round-7 proved TLP doesn't).
// Horner expert chain kept (full 8 for layers 0-2; 2-way split layer 3).
// W global offsets are linear across expert boundaries; A resets per expert.
// Grid = 256 blocks exactly (1/CU). XCD = flat%8 = bt%8: 4 bt-panels/XCD
// (2.23MB A L2-resident), W-slice shared by 4 co-resident bt-blocks.
// ---------------------------------------------------------------------------
__device__ __forceinline__ void gload16(const void* g, void* l) {
  __builtin_amdgcn_global_load_lds(
      (const __attribute__((address_space(1))) void*)g,
      (__attribute__((address_space(3))) void*)l, 16, 0, 0);
}

__global__ __launch_bounds__(512, 2) void moe_gemm_k(
    const ushort_t* __restrict__ inp,   // [B][J] bf16 (LN'd concat)
    const ushort_t* __restrict__ wT,    // [K][E*J] bf16 (pre-transposed)
    const float* __restrict__ scales,   // [B][8] Horner boundary scales
    float* __restrict__ outp,           // [nez][B][K] fp32 (partials if split)
    int J, int K, int ne) {
  const int Kd = E_EXP * J;
  const int nj = J >> 6;        // BK=64 tiles per expert
  const int nt = ne * nj;       // total K-tiles (even for all layers)
  __shared__ short As[2][32 * 512];   // [buf][sb*16+rg][lane*8] 64KB
  __shared__ short Wsm[2][16 * 512];  // [buf][sb*8+cg][lane*8]  32KB
  __shared__ float scale_s[256 * 9];  // [row][e] stride 9 (bank pad)

  const int t = threadIdx.x;
  const int w = t >> 6, l = t & 63;
  const int bt = blockIdx.x, ct = blockIdx.y, ez = blockIdx.z;
  const int e0 = ez * ne;
  outp += (size_t)ez * (size_t)B_ROWS * (size_t)K;

#pragma unroll
  for (int i = 0; i < 4; ++i) {
    int idx = t + (i << 9);  // 0..2047
    int rw = idx >> 3, e = idx & 7;
    scale_s[rw * 9 + e] = scales[(size_t)(bt * 256 + rw) * 8 + e];
  }

  // Staging bases. A: 32 blocks of 1KB (4/wave), W: 16 blocks (2/wave).
  // A block bi: sb=bi>>4, rg=bi&15 -> row bt*256+rg*16+(l&15), col sb*32+(l>>4)*8
  // W block bj: sb=bj>>3, cg=bj&7 -> row ct*128+cg*16+(l&15), col e0*J + ...
  size_t abase[4];
  size_t woffr[2];
#pragma unroll
  for (int i = 0; i < 4; ++i) {
    int bi = w * 4 + i;
    int sb = bi >> 4, rg = bi & 15;
    abase[i] = (size_t)(bt * 256 + rg * 16 + (l & 15)) * J +
               (sb * 32 + (l >> 4) * 8);
  }
#pragma unroll
  for (int i = 0; i < 2; ++i) {
    int bj = w * 2 + i;
    int sb = bj >> 3, cg = bj & 7;
    woffr[i] = (size_t)(ct * 128 + cg * 16 + (l & 15)) * Kd + (size_t)e0 * J +
               (sb * 32 + (l >> 4) * 8);
  }
  int acol = 0, sjt = 0;  // stage-side A column / jt-within-expert

  auto stage = [&](short* Ab, short* Wb) {
    short* Ad = Ab + (w * 4) * 512;
    gload16(inp + abase[0] + acol, Ad + 0 * 512);
    gload16(inp + abase[1] + acol, Ad + 1 * 512);
    gload16(inp + abase[2] + acol, Ad + 2 * 512);
    gload16(inp + abase[3] + acol, Ad + 3 * 512);
    short* Wd = Wb + (w * 2) * 512;
    gload16(wT + woffr[0], Wd + 0 * 512);
    gload16(wT + woffr[1], Wd + 1 * 512);
    woffr[0] += 64; woffr[1] += 64;
    acol += 64;
    if (++sjt == nj) { sjt = 0; acol = 0; }
  };

  f32x4 acc[4][4];
#pragma unroll
  for (int fm = 0; fm < 4; ++fm)
#pragma unroll
    for (int fn = 0; fn < 4; ++fn) acc[fm][fn] = (f32x4){0.f, 0.f, 0.f, 0.f};

  const int amBase = (w >> 1) * 4;  // A row-group base (wave row quadrant)
  const int wnBase = (w & 1) * 4;   // W col-group base (wave col half)

  auto compute = [&](const short* Ab, const short* Wb) {
    __builtin_amdgcn_s_setprio(1);
#pragma unroll
    for (int sb = 0; sb < 2; ++sb) {
      bf16x8 af[4], wf[4];
#pragma unroll
      for (int fm = 0; fm < 4; ++fm)
        af[fm] = *(const bf16x8*)(Ab + (sb * 16 + amBase + fm) * 512 + l * 8);
#pragma unroll
      for (int fn = 0; fn < 4; ++fn)
        wf[fn] = *(const bf16x8*)(Wb + (sb * 8 + wnBase + fn) * 512 + l * 8);
#pragma unroll
      for (int fm = 0; fm < 4; ++fm)
#pragma unroll
        for (int fn = 0; fn < 4; ++fn)
          acc[fm][fn] = __builtin_amdgcn_mfma_f32_16x16x32_bf16(
              af[fm], wf[fn], acc[fm][fn], 0, 0, 0);
    }
    __builtin_amdgcn_s_setprio(0);
  };

  int cjt = 0, cle = 0;  // compute-side jt / expert counters
  auto boundary = [&]() {
    if (cjt == nj - 1) {
      cjt = 0;
      int e = e0 + cle;
      ++cle;
#pragma unroll
      for (int fm = 0; fm < 4; ++fm) {
        int rbase = (w >> 1) * 64 + fm * 16 + ((l >> 4) << 2);
#pragma unroll
        for (int rr = 0; rr < 4; ++rr) {
          float rv = scale_s[(rbase + rr) * 9 + e];
#pragma unroll
          for (int fn = 0; fn < 4; ++fn) acc[fm][fn][rr] *= rv;
        }
      }
    } else {
      ++cjt;
    }
  };

  // prologue: tile 0 into buf 0 (barrier also covers scale_s ds_writes)
  stage(As[0], Wsm[0]);
  __syncthreads();

  for (int tp = 0; tp < nt; tp += 2) {
    // tile tp: compute buf0, stage tile tp+1 into buf1
    stage(As[1], Wsm[1]);
    compute(As[0], Wsm[0]);
    boundary();
    __syncthreads();  // drains stage(buf1); buf0 reads done
    // tile tp+1: compute buf1, stage tile tp+2 into buf0
    if (tp + 2 < nt) stage(As[0], Wsm[0]);
    compute(As[1], Wsm[1]);
    boundary();
    __syncthreads();
  }

  // epilogue: raw fp32 store (bias/ELU fused downstream)
#pragma unroll
  for (int fm = 0; fm < 4; ++fm) {
#pragma unroll
    for (int rr = 0; rr < 4; ++rr) {
      int row = (w >> 1) * 64 + fm * 16 + ((l >> 4) << 2) + rr;
      size_t orow = (size_t)(bt * 256 + row) * K + ct * 128;
#pragma unroll
      for (int fn = 0; fn < 4; ++fn) {
        int col = (w & 1) * 64 + fn * 16 + (l & 15);
        outp[orow + col] = acc[fm][fn][rr];
      }
    }
  }
}

// ---------------------------------------------------------------------------
// Final combine for layer 3 (2-way expert split, K=512, no activation):
//   out = p0 + p1 + coeff@bias
// ---------------------------------------------------------------------------
__global__ __launch_bounds__(256) void combine2_k(
    const float* __restrict__ pb, const float* __restrict__ cf,
    const float* __restrict__ bias, float* __restrict__ out, int K) {
  size_t i4 = (size_t)blockIdx.x * 256 + threadIdx.x;
  size_t total = (size_t)B_ROWS * (size_t)K;
  size_t base = i4 * 4;
  if (base >= total) return;
  int row = (int)(base / (size_t)K);
  int col = (int)(base % (size_t)K);
  size_t s4 = total >> 2;
  const f32x4* p4 = (const f32x4*)pb;
  f32x4 v = p4[i4] + p4[i4 + s4];
#pragma unroll
  for (int e = 0; e < 8; ++e) {
    float ce = cf[(size_t)row * 8 + e];
    f32x4 bv = *(const f32x4*)(bias + (size_t)e * K + col);
    v += ce * bv;
  }
  ((f32x4*)out)[i4] = v;
}

// ---------------------------------------------------------------------------
extern "C" void kernel_launch(void* const* d_in, const int* in_sizes, int n_in,
                              void* d_out, int out_size, void* d_ws, size_t ws_size,
                              hipStream_t stream) {
  const float* z   = (const float*)d_in[0];
  const float* c   = (const float*)d_in[1];
  const float* g0w = (const float*)d_in[2];
  const float* g0b = (const float*)d_in[3];
  const float* g1w = (const float*)d_in[4];
  const float* g1b = (const float*)d_in[5];
  const float* g2w = (const float*)d_in[6];
  const float* g2b = (const float*)d_in[7];
  const float* w0  = (const float*)d_in[8];
  const float* b0  = (const float*)d_in[9];
  const float* w1  = (const float*)d_in[10];
  const float* b1  = (const float*)d_in[11];
  const float* w2  = (const float*)d_in[12];
  const float* b2  = (const float*)d_in[13];
  const float* w3  = (const float*)d_in[14];
  const float* b3  = (const float*)d_in[15];

  char* ws = (char*)d_ws;
  size_t o = 0;
  auto alloc = [&](size_t bytes) {
    void* p = ws + o;
    o += (bytes + 255) & ~(size_t)255;
    return p;
  };
  ushort_t* wT0 = (ushort_t*)alloc((size_t)2560 * 1024 * 2);
  ushort_t* wT1 = (ushort_t*)alloc((size_t)8704 * 1024 * 2);
  ushort_t* wT2 = (ushort_t*)alloc((size_t)8704 * 1024 * 2);
  ushort_t* wT3 = (ushort_t*)alloc((size_t)8704 * 512 * 2);
  float*    cf   = (float*)alloc((size_t)B_ROWS * 8 * 4);
  float*    rat1 = (float*)alloc((size_t)B_ROWS * 8 * 4);
  float*    rat2 = (float*)alloc((size_t)B_ROWS * 8 * 4);
  ushort_t* inp  = (ushort_t*)alloc((size_t)B_ROWS * 1088 * 2);
  float*    hb   = (float*)alloc((size_t)B_ROWS * 1024 * 4);
  float*    pb   = (float*)alloc((size_t)2 * B_ROWS * 512 * 4);

  dim3 tb(64, 16);
  transpose_k<<<dim3(1024 / 64, 2560 / 64), tb, 0, stream>>>(w0, wT0, 2560, 1024);
  transpose_k<<<dim3(1024 / 64, 8704 / 64), tb, 0, stream>>>(w1, wT1, 8704, 1024);
  transpose_k<<<dim3(1024 / 64, 8704 / 64), tb, 0, stream>>>(w2, wT2, 8704, 1024);
  transpose_k<<<dim3(512 / 64, 8704 / 64), tb, 0, stream>>>(w3, wT3, 8704, 512);

  gate_k<<<B_ROWS / 4, 128, 0, stream>>>(z, c, g0w, g0b, g1w, g1b, g2w, g2b,
                                         cf, rat1, rat2);

  // layer 0: J=320, K=1024, full 8-expert Horner, grid 32x8 = 256 = 1/CU
  ln_concat_k<<<B_ROWS, 128, 0, stream>>>(z, c, nullptr, nullptr, inp, 256, 320);
  moe_gemm_k<<<dim3(32, 8, 1), 512, 0, stream>>>(inp, wT0, rat1, hb, 320, 1024, 8);
  // layer 1: J=1088, K=1024 (ln fuses b0-mix + elu)
  ln_concat_k<<<B_ROWS, 128, 0, stream>>>(z, hb, cf, b0, inp, 1024, 1088);
  moe_gemm_k<<<dim3(32, 8, 1), 512, 0, stream>>>(inp, wT1, rat1, hb, 1088, 1024, 8);
  // layer 2
  ln_concat_k<<<B_ROWS, 128, 0, stream>>>(z, hb, cf, b1, inp, 1024, 1088);
  moe_gemm_k<<<dim3(32, 8, 1), 512, 0, stream>>>(inp, wT2, rat1, hb, 1088, 1024, 8);
  // layer 3: J=1088, K=512, 2-way expert split, grid 32x4x2 = 256
  ln_concat_k<<<B_ROWS, 128, 0, stream>>>(z, hb, cf, b2, inp, 1024, 1088);
  moe_gemm_k<<<dim3(32, 4, 2), 512, 0, stream>>>(inp, wT3, rat2, pb, 1088, 512, 4);
  combine2_k<<<(B_ROWS * 512) / 1024, 256, 0, stream>>>(pb, cf, b3,
                                                        (float*)d_out, 512);
}

// Round 3
// 891.454 us; speedup vs baseline: 1.1674x; 1.1674x over previous
//
#include <hip/hip_runtime.h>
#include <cstdint>
#include <cstddef>

// Problem constants (fixed by the reference)
#define B_ROWS 8192
#define E_EXP  8

typedef unsigned short ushort_t;
typedef short bf16x8 __attribute__((ext_vector_type(8)));
typedef float f32x4  __attribute__((ext_vector_type(4)));

__device__ __forceinline__ ushort_t f2b(float f) {
  union { float f; unsigned int i; } v; v.f = f;
  unsigned int u = v.i;
  unsigned int r = (u + 0x7fffu + ((u >> 16) & 1u)) >> 16;
  return (ushort_t)r;
}
__device__ __forceinline__ float eluf(float x) {
  return x > 0.f ? x : (__expf(x) - 1.f);
}

// ---------------------------------------------------------------------------
// Weight transpose + fp32->bf16: w flat [R][C] -> wT [C][R] bf16.
// ---------------------------------------------------------------------------
__global__ void transpose_k(const float* __restrict__ src,
                            ushort_t* __restrict__ dst, int R, int C) {
  __shared__ ushort_t tile[64][65];
  int c0 = blockIdx.x * 64, r0 = blockIdx.y * 64;
  int x = threadIdx.x, y = threadIdx.y;
#pragma unroll
  for (int i = 0; i < 4; ++i)
    tile[y + 16 * i][x] = f2b(src[(size_t)(r0 + y + 16 * i) * C + c0 + x]);
  __syncthreads();
#pragma unroll
  for (int i = 0; i < 4; ++i)
    dst[(size_t)(c0 + y + 16 * i) * R + r0 + x] = tile[x][y + 16 * i];
}

// ---------------------------------------------------------------------------
// Gating MLP (pure fp32). Emits:
//   coeff[b][e]  softmax probs
//   rat1[b][e]   full-chain Horner scales (e<7: c_e/c_{e+1}; e=7: c_7)
//   rat2[b][e]   2-way split {0-3},{4-7}: e in {3,7}: c_e; else ratio
// ---------------------------------------------------------------------------
__global__ __launch_bounds__(128) void gate_k(
    const float* __restrict__ z, const float* __restrict__ c,
    const float* __restrict__ g0w, const float* __restrict__ g0b,
    const float* __restrict__ g1w, const float* __restrict__ g1b,
    const float* __restrict__ g2w, const float* __restrict__ g2b,
    float* __restrict__ coeff, float* __restrict__ rat1,
    float* __restrict__ rat2) {
  __shared__ float xs[4][320];
  __shared__ float h1[4][128];
  __shared__ float h2[4][128];
  __shared__ float lg[4][8];
  __shared__ float pr[4][8];
  int t = threadIdx.x;
  int r0 = blockIdx.x * 4;
  for (int idx = t; idx < 4 * 320; idx += 128) {
    int r = idx / 320, j = idx % 320;
    xs[r][j] = (j < 64) ? z[(size_t)(r0 + r) * 64 + j]
                        : c[(size_t)(r0 + r) * 256 + j - 64];
  }
  __syncthreads();
  {
    float bb = g0b[t];
    float a0 = bb, a1 = bb, a2 = bb, a3 = bb;
    for (int j = 0; j < 320; ++j) {
      float wv = g0w[j * 128 + t];
      a0 += xs[0][j] * wv; a1 += xs[1][j] * wv;
      a2 += xs[2][j] * wv; a3 += xs[3][j] * wv;
    }
    h1[0][t] = eluf(a0); h1[1][t] = eluf(a1);
    h1[2][t] = eluf(a2); h1[3][t] = eluf(a3);
  }
  __syncthreads();
  {
    float bb = g1b[t];
    float a0 = bb, a1 = bb, a2 = bb, a3 = bb;
    for (int j = 0; j < 128; ++j) {
      float wv = g1w[j * 128 + t];
      a0 += h1[0][j] * wv; a1 += h1[1][j] * wv;
      a2 += h1[2][j] * wv; a3 += h1[3][j] * wv;
    }
    h2[0][t] = eluf(a0); h2[1][t] = eluf(a1);
    h2[2][t] = eluf(a2); h2[3][t] = eluf(a3);
  }
  __syncthreads();
  if (t < 32) {
    int r = t >> 3, e = t & 7;
    float a = g2b[e];
    for (int j = 0; j < 128; ++j) a += h2[r][j] * g2w[j * 8 + e];
    lg[r][e] = a;
  }
  __syncthreads();
  if (t < 32) {
    int r = t >> 3, e = t & 7;
    float mx = lg[r][0];
#pragma unroll
    for (int i = 1; i < 8; ++i) mx = fmaxf(mx, lg[r][i]);
    float s = 0.f;
#pragma unroll
    for (int i = 0; i < 8; ++i) s += __expf(lg[r][i] - mx);
    float p = __expf(lg[r][e] - mx) / s;
    coeff[(size_t)(r0 + r) * 8 + e] = p;
    pr[r][e] = p;
  }
  __syncthreads();
  if (t < 32) {
    int r = t >> 3, e = t & 7;
    float pe = pr[r][e];
    float ratio = (e < 7) ? pe / fmaxf(pr[r][e + 1], 1e-30f) : pe;
    rat1[(size_t)(r0 + r) * 8 + e] = ratio;
    rat2[(size_t)(r0 + r) * 8 + e] = (e == 3 || e == 7) ? pe : ratio;
  }
}

// ---------------------------------------------------------------------------
// LayerNorm over concat([z_row, prev_row]) -> out [B][J] bf16.
//   cf != null : prev = elu(p0 + sum_e cf[row,e]*bias[e,:])  (post-GEMM layers)
//   cf == null : prev = p0 raw (layer-0 path reading c)
// ---------------------------------------------------------------------------
__global__ __launch_bounds__(128) void ln_concat_k(
    const float* __restrict__ z, const float* __restrict__ p0,
    const float* __restrict__ cf, const float* __restrict__ bias,
    ushort_t* __restrict__ out, int Pw, int J) {
  int row = blockIdx.x, t = threadIdx.x;
  float vals[9];
  int n = (J + 127) >> 7;
  float cr[8];
  if (cf) {
#pragma unroll
    for (int e = 0; e < 8; ++e) cr[e] = cf[(size_t)row * 8 + e];
  }
  float s = 0.f, s2 = 0.f;
  for (int k = 0; k < n; ++k) {
    int i = t + (k << 7);
    float x = 0.f;
    if (i < J) {
      if (i < 64) {
        x = z[(size_t)row * 64 + i];
      } else if (cf) {
        int j = i - 64;
        float v = p0[(size_t)row * Pw + j];
#pragma unroll
        for (int e = 0; e < 8; ++e) v += cr[e] * bias[(size_t)e * Pw + j];
        x = eluf(v);
      } else {
        x = p0[(size_t)row * Pw + i - 64];
      }
    }
    vals[k] = x; s += x; s2 += x * x;
  }
  for (int off = 32; off > 0; off >>= 1) {
    s += __shfl_down(s, off);
    s2 += __shfl_down(s2, off);
  }
  __shared__ float red[4];
  int wid = t >> 6, lane = t & 63;
  if (lane == 0) { red[wid * 2] = s; red[wid * 2 + 1] = s2; }
  __syncthreads();
  float S = red[0] + red[2], S2 = red[1] + red[3];
  float inv = 1.f / (float)J;
  float m = S * inv;
  float var = S2 * inv - m * m;
  float rstd = rsqrtf(var + 1e-5f);
  for (int k = 0; k < n; ++k) {
    int i = t + (k << 7);
    if (i < J) out[(size_t)row * J + i] = f2b((vals[k] - m) * rstd);
  }
}

// ---------------------------------------------------------------------------
// Fused MoE GEMM, round 9: counted-vmcnt 2-phase pipeline (T3+T4).
//
// Round-8 post-mortem: dbuf at 1 blk/CU gave ZERO speedup — all three prior
// structures are pinned at 287us because __syncthreads() == s_waitcnt
// vmcnt(0) lgkmcnt(0) + s_barrier: the barrier after stage(buf^1) drains the
// JUST-ISSUED prefetch, so every K-step serializes {stage -> L3-latency drain
// -> compute} regardless of buffering (m97-stall mechanism). Fix per the
// measured T4 recipe: raw `s_barrier` (no implicit drain) + counted
// `s_waitcnt vmcnt(6)` — waits only the PREVIOUS tile's 6 per-wave loads;
// the just-issued 6 stay in flight across the barrier and complete under
// compute. m218 measured counted-vs-drain0 at +38-73%.
//
// Geometry unchanged from round 8 (verified correct): 256x128 tile, 512 thr
// / 8 waves (4Mx2N, per-wave 64x64), BK=64, LDS A 2x32KB + W 2x16KB +
// scales 9KB = 105KB -> 1 block/CU. Full 8-expert Horner chain layers 0-2;
// 2-way expert split layer 3. Grid 256 blocks = 1/CU. XCD = bt%8.
// ---------------------------------------------------------------------------
__device__ __forceinline__ void gload16(const void* g, void* l) {
  __builtin_amdgcn_global_load_lds(
      (const __attribute__((address_space(1))) void*)g,
      (__attribute__((address_space(3))) void*)l, 16, 0, 0);
}

__global__ __launch_bounds__(512, 2) void moe_gemm_k(
    const ushort_t* __restrict__ inp,   // [B][J] bf16 (LN'd concat)
    const ushort_t* __restrict__ wT,    // [K][E*J] bf16 (pre-transposed)
    const float* __restrict__ scales,   // [B][8] Horner boundary scales
    float* __restrict__ outp,           // [nez][B][K] fp32 (partials if split)
    int J, int K, int ne) {
  const int Kd = E_EXP * J;
  const int nj = J >> 6;        // BK=64 tiles per expert
  const int nt = ne * nj;       // total K-tiles
  __shared__ short As[2][32 * 512];   // [buf][sb*16+rg][lane*8] 64KB
  __shared__ short Wsm[2][16 * 512];  // [buf][sb*8+cg][lane*8]  32KB
  __shared__ float scale_s[256 * 9];  // [row][e] stride 9 (bank pad)

  const int t = threadIdx.x;
  const int w = t >> 6, l = t & 63;
  const int bt = blockIdx.x, ct = blockIdx.y, ez = blockIdx.z;
  const int e0 = ez * ne;
  outp += (size_t)ez * (size_t)B_ROWS * (size_t)K;

#pragma unroll
  for (int i = 0; i < 4; ++i) {
    int idx = t + (i << 9);  // 0..2047
    int rw = idx >> 3, e = idx & 7;
    scale_s[rw * 9 + e] = scales[(size_t)(bt * 256 + rw) * 8 + e];
  }

  // Staging bases. A: 32 blocks of 1KB (4/wave), W: 16 blocks (2/wave).
  size_t abase[4];
  size_t woffr[2];
#pragma unroll
  for (int i = 0; i < 4; ++i) {
    int bi = w * 4 + i;
    int sb = bi >> 4, rg = bi & 15;
    abase[i] = (size_t)(bt * 256 + rg * 16 + (l & 15)) * J +
               (sb * 32 + (l >> 4) * 8);
  }
#pragma unroll
  for (int i = 0; i < 2; ++i) {
    int bj = w * 2 + i;
    int sb = bj >> 3, cg = bj & 7;
    woffr[i] = (size_t)(ct * 128 + cg * 16 + (l & 15)) * Kd + (size_t)e0 * J +
               (sb * 32 + (l >> 4) * 8);
  }
  int acol = 0, sjt = 0;  // stage-side A column / jt-within-expert

  auto stage = [&](short* Ab, short* Wb) {
    short* Ad = Ab + (w * 4) * 512;
    gload16(inp + abase[0] + acol, Ad + 0 * 512);
    gload16(inp + abase[1] + acol, Ad + 1 * 512);
    gload16(inp + abase[2] + acol, Ad + 2 * 512);
    gload16(inp + abase[3] + acol, Ad + 3 * 512);
    short* Wd = Wb + (w * 2) * 512;
    gload16(wT + woffr[0], Wd + 0 * 512);
    gload16(wT + woffr[1], Wd + 1 * 512);
    woffr[0] += 64; woffr[1] += 64;
    acol += 64;
    if (++sjt == nj) { sjt = 0; acol = 0; }
  };

  f32x4 acc[4][4];
#pragma unroll
  for (int fm = 0; fm < 4; ++fm)
#pragma unroll
    for (int fn = 0; fn < 4; ++fn) acc[fm][fn] = (f32x4){0.f, 0.f, 0.f, 0.f};

  const int amBase = (w >> 1) * 4;  // A row-group base (wave row quadrant)
  const int wnBase = (w & 1) * 4;   // W col-group base (wave col half)

  auto compute = [&](const short* Ab, const short* Wb) {
    __builtin_amdgcn_s_setprio(1);
#pragma unroll
    for (int sb = 0; sb < 2; ++sb) {
      bf16x8 af[4], wf[4];
#pragma unroll
      for (int fm = 0; fm < 4; ++fm)
        af[fm] = *(const bf16x8*)(Ab + (sb * 16 + amBase + fm) * 512 + l * 8);
#pragma unroll
      for (int fn = 0; fn < 4; ++fn)
        wf[fn] = *(const bf16x8*)(Wb + (sb * 8 + wnBase + fn) * 512 + l * 8);
#pragma unroll
      for (int fm = 0; fm < 4; ++fm)
#pragma unroll
        for (int fn = 0; fn < 4; ++fn)
          acc[fm][fn] = __builtin_amdgcn_mfma_f32_16x16x32_bf16(
              af[fm], wf[fn], acc[fm][fn], 0, 0, 0);
    }
    __builtin_amdgcn_s_setprio(0);
  };

  int cjt = 0, cle = 0;  // compute-side jt / expert counters
  auto boundary = [&]() {
    if (cjt == nj - 1) {
      cjt = 0;
      int e = e0 + cle;
      ++cle;
#pragma unroll
      for (int fm = 0; fm < 4; ++fm) {
        int rbase = (w >> 1) * 64 + fm * 16 + ((l >> 4) << 2);
#pragma unroll
        for (int rr = 0; rr < 4; ++rr) {
          float rv = scale_s[(rbase + rr) * 9 + e];
#pragma unroll
          for (int fn = 0; fn < 4; ++fn) acc[fm][fn][rr] *= rv;
        }
      }
    } else {
      ++cjt;
    }
  };

  // prologue: tile 0 into buf 0. One full-drain barrier (also makes the
  // scale_s ds_writes visible). After this, only counted waits.
  stage(As[0], Wsm[0]);
  __syncthreads();

  int buf = 0;
  for (int tp = 0; tp < nt; ++tp) {
    if (tp + 1 < nt) {
      // issue next tile's 6 loads, then wait only for the CURRENT tile's 6
      // (FIFO: oldest complete first). The new 6 stay in flight across the
      // barrier and land under compute().
      stage(As[buf ^ 1], Wsm[buf ^ 1]);
      asm volatile("s_waitcnt vmcnt(6)" ::: "memory");
    } else {
      asm volatile("s_waitcnt vmcnt(0)" ::: "memory");
    }
    asm volatile("s_barrier" ::: "memory");   // raw barrier: no vmcnt drain
    compute(As[buf], Wsm[buf]);
    boundary();
    asm volatile("s_barrier" ::: "memory");   // all reads of buf done
    buf ^= 1;
  }

  // epilogue: raw fp32 store (bias/ELU fused downstream)
#pragma unroll
  for (int fm = 0; fm < 4; ++fm) {
#pragma unroll
    for (int rr = 0; rr < 4; ++rr) {
      int row = (w >> 1) * 64 + fm * 16 + ((l >> 4) << 2) + rr;
      size_t orow = (size_t)(bt * 256 + row) * K + ct * 128;
#pragma unroll
      for (int fn = 0; fn < 4; ++fn) {
        int col = (w & 1) * 64 + fn * 16 + (l & 15);
        outp[orow + col] = acc[fm][fn][rr];
      }
    }
  }
}

// ---------------------------------------------------------------------------
// Final combine for layer 3 (2-way expert split, K=512, no activation):
//   out = p0 + p1 + coeff@bias
// ---------------------------------------------------------------------------
__global__ __launch_bounds__(256) void combine2_k(
    const float* __restrict__ pb, const float* __restrict__ cf,
    const float* __restrict__ bias, float* __restrict__ out, int K) {
  size_t i4 = (size_t)blockIdx.x * 256 + threadIdx.x;
  size_t total = (size_t)B_ROWS * (size_t)K;
  size_t base = i4 * 4;
  if (base >= total) return;
  int row = (int)(base / (size_t)K);
  int col = (int)(base % (size_t)K);
  size_t s4 = total >> 2;
  const f32x4* p4 = (const f32x4*)pb;
  f32x4 v = p4[i4] + p4[i4 + s4];
#pragma unroll
  for (int e = 0; e < 8; ++e) {
    float ce = cf[(size_t)row * 8 + e];
    f32x4 bv = *(const f32x4*)(bias + (size_t)e * K + col);
    v += ce * bv;
  }
  ((f32x4*)out)[i4] = v;
}

// ---------------------------------------------------------------------------
extern "C" void kernel_launch(void* const* d_in, const int* in_sizes, int n_in,
                              void* d_out, int out_size, void* d_ws, size_t ws_size,
                              hipStream_t stream) {
  const float* z   = (const float*)d_in[0];
  const float* c   = (const float*)d_in[1];
  const float* g0w = (const float*)d_in[2];
  const float* g0b = (const float*)d_in[3];
  const float* g1w = (const float*)d_in[4];
  const float* g1b = (const float*)d_in[5];
  const float* g2w = (const float*)d_in[6];
  const float* g2b = (const float*)d_in[7];
  const float* w0  = (const float*)d_in[8];
  const float* b0  = (const float*)d_in[9];
  const float* w1  = (const float*)d_in[10];
  const float* b1  = (const float*)d_in[11];
  const float* w2  = (const float*)d_in[12];
  const float* b2  = (const float*)d_in[13];
  const float* w3  = (const float*)d_in[14];
  const float* b3  = (const float*)d_in[15];

  char* ws = (char*)d_ws;
  size_t o = 0;
  auto alloc = [&](size_t bytes) {
    void* p = ws + o;
    o += (bytes + 255) & ~(size_t)255;
    return p;
  };
  ushort_t* wT0 = (ushort_t*)alloc((size_t)2560 * 1024 * 2);
  ushort_t* wT1 = (ushort_t*)alloc((size_t)8704 * 1024 * 2);
  ushort_t* wT2 = (ushort_t*)alloc((size_t)8704 * 1024 * 2);
  ushort_t* wT3 = (ushort_t*)alloc((size_t)8704 * 512 * 2);
  float*    cf   = (float*)alloc((size_t)B_ROWS * 8 * 4);
  float*    rat1 = (float*)alloc((size_t)B_ROWS * 8 * 4);
  float*    rat2 = (float*)alloc((size_t)B_ROWS * 8 * 4);
  ushort_t* inp  = (ushort_t*)alloc((size_t)B_ROWS * 1088 * 2);
  float*    hb   = (float*)alloc((size_t)B_ROWS * 1024 * 4);
  float*    pb   = (float*)alloc((size_t)2 * B_ROWS * 512 * 4);

  dim3 tb(64, 16);
  transpose_k<<<dim3(1024 / 64, 2560 / 64), tb, 0, stream>>>(w0, wT0, 2560, 1024);
  transpose_k<<<dim3(1024 / 64, 8704 / 64), tb, 0, stream>>>(w1, wT1, 8704, 1024);
  transpose_k<<<dim3(1024 / 64, 8704 / 64), tb, 0, stream>>>(w2, wT2, 8704, 1024);
  transpose_k<<<dim3(512 / 64, 8704 / 64), tb, 0, stream>>>(w3, wT3, 8704, 512);

  gate_k<<<B_ROWS / 4, 128, 0, stream>>>(z, c, g0w, g0b, g1w, g1b, g2w, g2b,
                                         cf, rat1, rat2);

  // layer 0: J=320, K=1024, full 8-expert Horner, grid 32x8 = 256 = 1/CU
  ln_concat_k<<<B_ROWS, 128, 0, stream>>>(z, c, nullptr, nullptr, inp, 256, 320);
  moe_gemm_k<<<dim3(32, 8, 1), 512, 0, stream>>>(inp, wT0, rat1, hb, 320, 1024, 8);
  // layer 1: J=1088, K=1024 (ln fuses b0-mix + elu)
  ln_concat_k<<<B_ROWS, 128, 0, stream>>>(z, hb, cf, b0, inp, 1024, 1088);
  moe_gemm_k<<<dim3(32, 8, 1), 512, 0, stream>>>(inp, wT1, rat1, hb, 1088, 1024, 8);
  // layer 2
  ln_concat_k<<<B_ROWS, 128, 0, stream>>>(z, hb, cf, b1, inp, 1024, 1088);
  moe_gemm_k<<<dim3(32, 8, 1), 512, 0, stream>>>(inp, wT2, rat1, hb, 1088, 1024, 8);
  // layer 3: J=1088, K=512, 2-way expert split, grid 32x4x2 = 256
  ln_concat_k<<<B_ROWS, 128, 0, stream>>>(z, hb, cf, b2, inp, 1024, 1088);
  moe_gemm_k<<<dim3(32, 4, 2), 512, 0, stream>>>(inp, wT3, rat2, pb, 1088, 512, 4);
  combine2_k<<<(B_ROWS * 512) / 1024, 256, 0, stream>>>(pb, cf, b3,
                                                        (float*)d_out, 512);
}

// Round 4
// 712.519 us; speedup vs baseline: 1.4605x; 1.2511x over previous
//
#include <hip/hip_runtime.h>
#include <cstdint>
#include <cstddef>

// Problem constants (fixed by the reference)
#define B_ROWS 8192
#define E_EXP  8

typedef unsigned short ushort_t;
typedef short bf16x8 __attribute__((ext_vector_type(8)));
typedef float f32x4  __attribute__((ext_vector_type(4)));

__device__ __forceinline__ ushort_t f2b(float f) {
  union { float f; unsigned int i; } v; v.f = f;
  unsigned int u = v.i;
  unsigned int r = (u + 0x7fffu + ((u >> 16) & 1u)) >> 16;
  return (ushort_t)r;
}
__device__ __forceinline__ float eluf(float x) {
  return x > 0.f ? x : (__expf(x) - 1.f);
}

// ---------------------------------------------------------------------------
// Weight transpose + fp32->bf16: w flat [R][C] -> wT [C][R] bf16.
// ---------------------------------------------------------------------------
__global__ void transpose_k(const float* __restrict__ src,
                            ushort_t* __restrict__ dst, int R, int C) {
  __shared__ ushort_t tile[64][65];
  int c0 = blockIdx.x * 64, r0 = blockIdx.y * 64;
  int x = threadIdx.x, y = threadIdx.y;
#pragma unroll
  for (int i = 0; i < 4; ++i)
    tile[y + 16 * i][x] = f2b(src[(size_t)(r0 + y + 16 * i) * C + c0 + x]);
  __syncthreads();
#pragma unroll
  for (int i = 0; i < 4; ++i)
    dst[(size_t)(c0 + y + 16 * i) * R + r0 + x] = tile[x][y + 16 * i];
}

// ---------------------------------------------------------------------------
// Gating MLP (pure fp32). Emits:
//   coeff[b][e]  softmax probs
//   rat2[b][e]   2-way split {0-3},{4-7}: e in {3,7}: c_e; else c_e/c_{e+1}
//   rat4[b][e]   4-way split {0,1}..{6,7}: e odd: c_e; e even: c_e/c_{e+1}
// ---------------------------------------------------------------------------
__global__ __launch_bounds__(128) void gate_k(
    const float* __restrict__ z, const float* __restrict__ c,
    const float* __restrict__ g0w, const float* __restrict__ g0b,
    const float* __restrict__ g1w, const float* __restrict__ g1b,
    const float* __restrict__ g2w, const float* __restrict__ g2b,
    float* __restrict__ coeff, float* __restrict__ rat2,
    float* __restrict__ rat4) {
  __shared__ float xs[4][320];
  __shared__ float h1[4][128];
  __shared__ float h2[4][128];
  __shared__ float lg[4][8];
  __shared__ float pr[4][8];
  int t = threadIdx.x;
  int r0 = blockIdx.x * 4;
  for (int idx = t; idx < 4 * 320; idx += 128) {
    int r = idx / 320, j = idx % 320;
    xs[r][j] = (j < 64) ? z[(size_t)(r0 + r) * 64 + j]
                        : c[(size_t)(r0 + r) * 256 + j - 64];
  }
  __syncthreads();
  {
    float bb = g0b[t];
    float a0 = bb, a1 = bb, a2 = bb, a3 = bb;
    for (int j = 0; j < 320; ++j) {
      float wv = g0w[j * 128 + t];
      a0 += xs[0][j] * wv; a1 += xs[1][j] * wv;
      a2 += xs[2][j] * wv; a3 += xs[3][j] * wv;
    }
    h1[0][t] = eluf(a0); h1[1][t] = eluf(a1);
    h1[2][t] = eluf(a2); h1[3][t] = eluf(a3);
  }
  __syncthreads();
  {
    float bb = g1b[t];
    float a0 = bb, a1 = bb, a2 = bb, a3 = bb;
    for (int j = 0; j < 128; ++j) {
      float wv = g1w[j * 128 + t];
      a0 += h1[0][j] * wv; a1 += h1[1][j] * wv;
      a2 += h1[2][j] * wv; a3 += h1[3][j] * wv;
    }
    h2[0][t] = eluf(a0); h2[1][t] = eluf(a1);
    h2[2][t] = eluf(a2); h2[3][t] = eluf(a3);
  }
  __syncthreads();
  if (t < 32) {
    int r = t >> 3, e = t & 7;
    float a = g2b[e];
    for (int j = 0; j < 128; ++j) a += h2[r][j] * g2w[j * 8 + e];
    lg[r][e] = a;
  }
  __syncthreads();
  if (t < 32) {
    int r = t >> 3, e = t & 7;
    float mx = lg[r][0];
#pragma unroll
    for (int i = 1; i < 8; ++i) mx = fmaxf(mx, lg[r][i]);
    float s = 0.f;
#pragma unroll
    for (int i = 0; i < 8; ++i) s += __expf(lg[r][i] - mx);
    float p = __expf(lg[r][e] - mx) / s;
    coeff[(size_t)(r0 + r) * 8 + e] = p;
    pr[r][e] = p;
  }
  __syncthreads();
  if (t < 32) {
    int r = t >> 3, e = t & 7;
    float pe = pr[r][e];
    float ratio = (e < 7) ? pe / fmaxf(pr[r][e + 1], 1e-30f) : pe;
    rat2[(size_t)(r0 + r) * 8 + e] = (e == 3 || e == 7) ? pe : ratio;
    rat4[(size_t)(r0 + r) * 8 + e] = (e & 1) ? pe : ratio;
  }
}

// ---------------------------------------------------------------------------
// LayerNorm over concat([z_row, prev_row]) -> out [B][J] bf16.
//   p1 != null : prev = elu(p0 + p1 + sum_e cf[row,e]*bias[e,:])
//   p1 == null : prev = p0 raw (layer-0 path reading c)
// ---------------------------------------------------------------------------
__global__ __launch_bounds__(128) void ln_concat_k(
    const float* __restrict__ z, const float* __restrict__ p0,
    const float* __restrict__ p1, const float* __restrict__ cf,
    const float* __restrict__ bias, ushort_t* __restrict__ out,
    int Pw, int J) {
  int row = blockIdx.x, t = threadIdx.x;
  float vals[9];
  int n = (J + 127) >> 7;
  float cr[8];
  if (p1) {
#pragma unroll
    for (int e = 0; e < 8; ++e) cr[e] = cf[(size_t)row * 8 + e];
  }
  float s = 0.f, s2 = 0.f;
  for (int k = 0; k < n; ++k) {
    int i = t + (k << 7);
    float x = 0.f;
    if (i < J) {
      if (i < 64) {
        x = z[(size_t)row * 64 + i];
      } else if (p1) {
        int j = i - 64;
        float v = p0[(size_t)row * Pw + j] + p1[(size_t)row * Pw + j];
#pragma unroll
        for (int e = 0; e < 8; ++e) v += cr[e] * bias[(size_t)e * Pw + j];
        x = eluf(v);
      } else {
        x = p0[(size_t)row * Pw + i - 64];
      }
    }
    vals[k] = x; s += x; s2 += x * x;
  }
  for (int off = 32; off > 0; off >>= 1) {
    s += __shfl_down(s, off);
    s2 += __shfl_down(s2, off);
  }
  __shared__ float red[4];
  int wid = t >> 6, lane = t & 63;
  if (lane == 0) { red[wid * 2] = s; red[wid * 2 + 1] = s2; }
  __syncthreads();
  float S = red[0] + red[2], S2 = red[1] + red[3];
  float inv = 1.f / (float)J;
  float m = S * inv;
  float var = S2 * inv - m * m;
  float rstd = rsqrtf(var + 1e-5f);
  for (int k = 0; k < n; ++k) {
    int i = t + (k << 7);
    if (i < J) out[(size_t)row * J + i] = f2b((vals[k] - m) * rstd);
  }
}

// ---------------------------------------------------------------------------
// Fused MoE GEMM, round 10: 256x256 tile, 4-sub-phase interleave per K-tile
// (T3 full structure), counted vmcnt(4) twice per K-tile, never 0 mid-loop.
//
// Round-9 post-mortem: counted-vmcnt 2-phase verified (+22%: 287->236us,
// MfmaUtil 26%) — we are AT the documented 2-phase ceiling (~620-680 TF).
// The next documented lever is the 8-phase-style sub-tile interleave:
//   P1{stage A'(k0) | read Bk0 + A m0-3 | 16 MFMA}
//   P2{stage W'(k0) | read A m4-7      | 16 MFMA | vmcnt(4); barrier}
//   P3{stage A'(k1) | read Bk1 + A m0-3 | 16 MFMA}
//   P4{stage W'(k1) | read A m4-7      | 16 MFMA | vmcnt(4); barrier}
// Each staged 16KB unit lands >=3 phases before first use (FIFO verified).
// 256x256 tile also halves LDS-read per FLOP (B-frags reused across m-halves,
// per-wave 128x64: 24 b128 reads / 64 MFMA vs 16/32 before).
//
// 512 thr / 8 waves (2M x 4N), per-wave 128x64, acc 8x4 f32x4 = 128 VGPR.
// LDS: A 2buf x 2ks x 16KB + W same = 128KB + scales 9KB -> 1 block/CU.
// Grid 256 blocks = 1/CU via expert split: layers 0-2 ez=2 (rat2 scales,
// partials combined in ln_concat_k), layer 3 ez=4 (rat4, combine4_k).
// W offsets linear across experts; A col resets per expert. XCD = bt%8.
// ---------------------------------------------------------------------------
__device__ __forceinline__ void gload16(const void* g, void* l) {
  __builtin_amdgcn_global_load_lds(
      (const __attribute__((address_space(1))) void*)g,
      (__attribute__((address_space(3))) void*)l, 16, 0, 0);
}

#define LOAD_B(Wb)                                                         \
  _Pragma("unroll") for (int fn = 0; fn < 4; ++fn) bf[fn] =                \
      *(const bf16x8*)((Wb) + (wn * 4 + fn) * 512 + l * 8);

#define QUAD(Ab, MB)                                                       \
  {                                                                        \
    bf16x8 af[4];                                                          \
    _Pragma("unroll") for (int q = 0; q < 4; ++q) af[q] =                  \
        *(const bf16x8*)((Ab) + (wm * 8 + (MB) + q) * 512 + l * 8);        \
    __builtin_amdgcn_s_setprio(1);                                         \
    _Pragma("unroll") for (int q = 0; q < 4; ++q)                          \
        _Pragma("unroll") for (int fn = 0; fn < 4; ++fn) acc[(MB) + q][fn] = \
            __builtin_amdgcn_mfma_f32_16x16x32_bf16(af[q], bf[fn],         \
                                                    acc[(MB) + q][fn], 0, 0, 0); \
    __builtin_amdgcn_s_setprio(0);                                         \
  }

__global__ __launch_bounds__(512, 2) void moe_gemm_k(
    const ushort_t* __restrict__ inp,   // [B][J] bf16 (LN'd concat)
    const ushort_t* __restrict__ wT,    // [K][E*J] bf16 (pre-transposed)
    const float* __restrict__ scales,   // [B][8] Horner boundary scales
    float* __restrict__ outp,           // [nez][B][K] fp32 partials
    int J, int K, int ne) {
  const int Kd = E_EXP * J;
  const int nj = J >> 6;        // BK=64 tiles per expert
  const int nt = ne * nj;       // total K-tiles for this block's expert range
  __shared__ short As[2][2][16 * 512];   // [buf][ks][g*512 + l*8]  64KB
  __shared__ short Wsm[2][2][16 * 512];  // [buf][ks][h*512 + l*8]  64KB
  __shared__ float scale_s[256 * 9];     // [row][e] stride 9 (bank pad)

  const int t = threadIdx.x;
  const int w = t >> 6, l = t & 63;
  const int wm = w >> 2, wn = w & 3;     // 2M x 4N wave layout
  const int bt = blockIdx.x, ct = blockIdx.y, ez = blockIdx.z;
  const int e0 = ez * ne;
  outp += (size_t)ez * (size_t)B_ROWS * (size_t)K;

#pragma unroll
  for (int i = 0; i < 4; ++i) {
    int idx = t + (i << 9);  // 0..2047
    int rw = idx >> 3, e = idx & 7;
    scale_s[rw * 9 + e] = scales[(size_t)(bt * 256 + rw) * 8 + e];
  }

  // Stage bases: per wave 2 row-group blocks (1KB each) per 16KB unit.
  size_t abase[2], wbase[2];
#pragma unroll
  for (int i = 0; i < 2; ++i) {
    int g = w * 2 + i;
    abase[i] = (size_t)(bt * 256 + g * 16 + (l & 15)) * J + ((l >> 4) * 8);
    wbase[i] = (size_t)(ct * 256 + g * 16 + (l & 15)) * Kd + (size_t)e0 * J +
               ((l >> 4) * 8);
  }
  int s_acol = 0, s_wcol = 0, sjt = 0;  // stage-side counters (next tile)

  auto stageA = [&](int nb, int ks) {
    short* d = &As[nb][ks][w * 2 * 512];
    gload16(inp + abase[0] + s_acol + ks * 32, d);
    gload16(inp + abase[1] + s_acol + ks * 32, d + 512);
  };
  auto stageW = [&](int nb, int ks) {
    short* d = &Wsm[nb][ks][w * 2 * 512];
    gload16(wT + wbase[0] + s_wcol + ks * 32, d);
    gload16(wT + wbase[1] + s_wcol + ks * 32, d + 512);
  };
  auto advance = [&]() {
    s_wcol += 64;
    if (++sjt == nj) { sjt = 0; s_acol = 0; } else { s_acol += 64; }
  };

  f32x4 acc[8][4];
#pragma unroll
  for (int fm = 0; fm < 8; ++fm)
#pragma unroll
    for (int fn = 0; fn < 4; ++fn) acc[fm][fn] = (f32x4){0.f, 0.f, 0.f, 0.f};

  // prologue: tile 0 fully staged into buf 0; full drain once (also
  // publishes scale_s).
  stageA(0, 0); stageW(0, 0); stageA(0, 1); stageW(0, 1); advance();
  __syncthreads();

  int cjt = 0, cle = 0;  // compute-side counters
  for (int tp = 0; tp < nt; ++tp) {
    const int b = tp & 1, nb = b ^ 1;
    const bool more = (tp + 1 < nt);
    const short* Ab0 = &As[b][0][0];
    const short* Ab1 = &As[b][1][0];
    const short* Wb0 = &Wsm[b][0][0];
    const short* Wb1 = &Wsm[b][1][0];
    bf16x8 bf[4];

    // ---- phase 1: stage A'(k0); read B k0 + A k0 m0-3; 16 MFMA
    if (more) stageA(nb, 0);
    LOAD_B(Wb0);
    QUAD(Ab0, 0);
    // ---- phase 2: stage W'(k0); A k0 m4-7; 16 MFMA; wait; barrier
    if (more) stageW(nb, 0);
    QUAD(Ab0, 4);
    if (more) asm volatile("s_waitcnt vmcnt(4)" ::: "memory");
    else      asm volatile("s_waitcnt vmcnt(0)" ::: "memory");
    asm volatile("s_barrier" ::: "memory");
    // ---- phase 3: stage A'(k1); read B k1 + A k1 m0-3; 16 MFMA
    if (more) stageA(nb, 1);
    LOAD_B(Wb1);
    QUAD(Ab1, 0);
    // ---- phase 4: stage W'(k1); A k1 m4-7; 16 MFMA; boundary; wait; barrier
    if (more) { stageW(nb, 1); advance(); }
    QUAD(Ab1, 4);
    if (++cjt == nj) {
      cjt = 0;
      int e = e0 + cle;
      ++cle;
#pragma unroll
      for (int fi = 0; fi < 8; ++fi) {
        int rbase = wm * 128 + fi * 16 + ((l >> 4) << 2);
#pragma unroll
        for (int rr = 0; rr < 4; ++rr) {
          float rv = scale_s[(rbase + rr) * 9 + e];
#pragma unroll
          for (int fn = 0; fn < 4; ++fn) acc[fi][fn][rr] *= rv;
        }
      }
    }
    if (more) asm volatile("s_waitcnt vmcnt(4)" ::: "memory");
    else      asm volatile("s_waitcnt vmcnt(0)" ::: "memory");
    asm volatile("s_barrier" ::: "memory");
  }

  // epilogue: raw fp32 partial store (bias/ELU fused downstream)
#pragma unroll
  for (int fi = 0; fi < 8; ++fi) {
#pragma unroll
    for (int rr = 0; rr < 4; ++rr) {
      int row = wm * 128 + fi * 16 + ((l >> 4) << 2) + rr;
      size_t orow = (size_t)(bt * 256 + row) * K + ct * 256;
#pragma unroll
      for (int fn = 0; fn < 4; ++fn) {
        int col = wn * 64 + fn * 16 + (l & 15);
        outp[orow + col] = acc[fi][fn][rr];
      }
    }
  }
}

// ---------------------------------------------------------------------------
// Final combine for layer 3 (4-way expert split, K=512, no activation):
//   out = p0+p1+p2+p3 + coeff@bias
// ---------------------------------------------------------------------------
__global__ __launch_bounds__(256) void combine4_k(
    const float* __restrict__ pb, const float* __restrict__ cf,
    const float* __restrict__ bias, float* __restrict__ out, int K) {
  size_t i4 = (size_t)blockIdx.x * 256 + threadIdx.x;
  size_t total = (size_t)B_ROWS * (size_t)K;
  size_t base = i4 * 4;
  if (base >= total) return;
  int row = (int)(base / (size_t)K);
  int col = (int)(base % (size_t)K);
  size_t s4 = total >> 2;  // partial stride in f32x4 units
  const f32x4* p4 = (const f32x4*)pb;
  f32x4 v = p4[i4] + p4[i4 + s4] + p4[i4 + 2 * s4] + p4[i4 + 3 * s4];
#pragma unroll
  for (int e = 0; e < 8; ++e) {
    float ce = cf[(size_t)row * 8 + e];
    f32x4 bv = *(const f32x4*)(bias + (size_t)e * K + col);
    v += ce * bv;
  }
  ((f32x4*)out)[i4] = v;
}

// ---------------------------------------------------------------------------
extern "C" void kernel_launch(void* const* d_in, const int* in_sizes, int n_in,
                              void* d_out, int out_size, void* d_ws, size_t ws_size,
                              hipStream_t stream) {
  const float* z   = (const float*)d_in[0];
  const float* c   = (const float*)d_in[1];
  const float* g0w = (const float*)d_in[2];
  const float* g0b = (const float*)d_in[3];
  const float* g1w = (const float*)d_in[4];
  const float* g1b = (const float*)d_in[5];
  const float* g2w = (const float*)d_in[6];
  const float* g2b = (const float*)d_in[7];
  const float* w0  = (const float*)d_in[8];
  const float* b0  = (const float*)d_in[9];
  const float* w1  = (const float*)d_in[10];
  const float* b1  = (const float*)d_in[11];
  const float* w2  = (const float*)d_in[12];
  const float* b2  = (const float*)d_in[13];
  const float* w3  = (const float*)d_in[14];
  const float* b3  = (const float*)d_in[15];

  char* ws = (char*)d_ws;
  size_t o = 0;
  auto alloc = [&](size_t bytes) {
    void* p = ws + o;
    o += (bytes + 255) & ~(size_t)255;
    return p;
  };
  ushort_t* wT0 = (ushort_t*)alloc((size_t)2560 * 1024 * 2);
  ushort_t* wT1 = (ushort_t*)alloc((size_t)8704 * 1024 * 2);
  ushort_t* wT2 = (ushort_t*)alloc((size_t)8704 * 1024 * 2);
  ushort_t* wT3 = (ushort_t*)alloc((size_t)8704 * 512 * 2);
  float*    cf   = (float*)alloc((size_t)B_ROWS * 8 * 4);
  float*    rat2 = (float*)alloc((size_t)B_ROWS * 8 * 4);
  float*    rat4 = (float*)alloc((size_t)B_ROWS * 8 * 4);
  ushort_t* inp  = (ushort_t*)alloc((size_t)B_ROWS * 1088 * 2);
  float*    pb   = (float*)alloc((size_t)2 * B_ROWS * 1024 * 4);  // partials

  dim3 tb(64, 16);
  transpose_k<<<dim3(1024 / 64, 2560 / 64), tb, 0, stream>>>(w0, wT0, 2560, 1024);
  transpose_k<<<dim3(1024 / 64, 8704 / 64), tb, 0, stream>>>(w1, wT1, 8704, 1024);
  transpose_k<<<dim3(1024 / 64, 8704 / 64), tb, 0, stream>>>(w2, wT2, 8704, 1024);
  transpose_k<<<dim3(512 / 64, 8704 / 64), tb, 0, stream>>>(w3, wT3, 8704, 512);

  gate_k<<<B_ROWS / 4, 128, 0, stream>>>(z, c, g0w, g0b, g1w, g1b, g2w, g2b,
                                         cf, rat2, rat4);

  float* p1v = pb + (size_t)B_ROWS * 1024;

  // layer 0: J=320, K=1024, 2-way expert split (ne=4), grid 32x4x2 = 256
  ln_concat_k<<<B_ROWS, 128, 0, stream>>>(z, c, nullptr, nullptr, nullptr,
                                          inp, 256, 320);
  moe_gemm_k<<<dim3(32, 4, 2), 512, 0, stream>>>(inp, wT0, rat2, pb, 320, 1024, 4);
  // layer 1: J=1088, K=1024 (ln fuses partial combine + b0-mix + elu)
  ln_concat_k<<<B_ROWS, 128, 0, stream>>>(z, pb, p1v, cf, b0, inp, 1024, 1088);
  moe_gemm_k<<<dim3(32, 4, 2), 512, 0, stream>>>(inp, wT1, rat2, pb, 1088, 1024, 4);
  // layer 2
  ln_concat_k<<<B_ROWS, 128, 0, stream>>>(z, pb, p1v, cf, b1, inp, 1024, 1088);
  moe_gemm_k<<<dim3(32, 4, 2), 512, 0, stream>>>(inp, wT2, rat2, pb, 1088, 1024, 4);
  // layer 3: J=1088, K=512, 4-way expert split (ne=2), grid 32x2x4 = 256
  ln_concat_k<<<B_ROWS, 128, 0, stream>>>(z, pb, p1v, cf, b2, inp, 1024, 1088);
  moe_gemm_k<<<dim3(32, 2, 4), 512, 0, stream>>>(inp, wT3, rat4, pb, 1088, 512, 2);
  combine4_k<<<(B_ROWS * 512) / 1024, 256, 0, stream>>>(pb, cf, b3,
                                                        (float*)d_out, 512);
}

// Round 5
// 700.502 us; speedup vs baseline: 1.4856x; 1.0172x over previous
//
#include <hip/hip_runtime.h>
#include <cstdint>
#include <cstddef>

// Problem constants (fixed by the reference)
#define B_ROWS 8192
#define E_EXP  8

typedef unsigned short ushort_t;
typedef short bf16x8 __attribute__((ext_vector_type(8)));
typedef float f32x4  __attribute__((ext_vector_type(4)));

__device__ __forceinline__ ushort_t f2b(float f) {
  union { float f; unsigned int i; } v; v.f = f;
  unsigned int u = v.i;
  unsigned int r = (u + 0x7fffu + ((u >> 16) & 1u)) >> 16;
  return (ushort_t)r;
}
__device__ __forceinline__ float eluf(float x) {
  return x > 0.f ? x : (__expf(x) - 1.f);
}

// ---------------------------------------------------------------------------
// Weight transpose + fp32->bf16: w flat [R][C] -> wT [C][R] bf16.
// ---------------------------------------------------------------------------
__global__ void transpose_k(const float* __restrict__ src,
                            ushort_t* __restrict__ dst, int R, int C) {
  __shared__ ushort_t tile[64][65];
  int c0 = blockIdx.x * 64, r0 = blockIdx.y * 64;
  int x = threadIdx.x, y = threadIdx.y;
#pragma unroll
  for (int i = 0; i < 4; ++i)
    tile[y + 16 * i][x] = f2b(src[(size_t)(r0 + y + 16 * i) * C + c0 + x]);
  __syncthreads();
#pragma unroll
  for (int i = 0; i < 4; ++i)
    dst[(size_t)(c0 + y + 16 * i) * R + r0 + x] = tile[x][y + 16 * i];
}

// ---------------------------------------------------------------------------
// Gating MLP (pure fp32). Emits:
//   coeff[b][e]  softmax probs
//   rat2[b][e]   2-way split {0-3},{4-7}: e in {3,7}: c_e; else c_e/c_{e+1}
//   rat4[b][e]   4-way split {0,1}..{6,7}: e odd: c_e; e even: c_e/c_{e+1}
// ---------------------------------------------------------------------------
__global__ __launch_bounds__(128) void gate_k(
    const float* __restrict__ z, const float* __restrict__ c,
    const float* __restrict__ g0w, const float* __restrict__ g0b,
    const float* __restrict__ g1w, const float* __restrict__ g1b,
    const float* __restrict__ g2w, const float* __restrict__ g2b,
    float* __restrict__ coeff, float* __restrict__ rat2,
    float* __restrict__ rat4) {
  __shared__ float xs[4][320];
  __shared__ float h1[4][128];
  __shared__ float h2[4][128];
  __shared__ float lg[4][8];
  __shared__ float pr[4][8];
  int t = threadIdx.x;
  int r0 = blockIdx.x * 4;
  for (int idx = t; idx < 4 * 320; idx += 128) {
    int r = idx / 320, j = idx % 320;
    xs[r][j] = (j < 64) ? z[(size_t)(r0 + r) * 64 + j]
                        : c[(size_t)(r0 + r) * 256 + j - 64];
  }
  __syncthreads();
  {
    float bb = g0b[t];
    float a0 = bb, a1 = bb, a2 = bb, a3 = bb;
    for (int j = 0; j < 320; ++j) {
      float wv = g0w[j * 128 + t];
      a0 += xs[0][j] * wv; a1 += xs[1][j] * wv;
      a2 += xs[2][j] * wv; a3 += xs[3][j] * wv;
    }
    h1[0][t] = eluf(a0); h1[1][t] = eluf(a1);
    h1[2][t] = eluf(a2); h1[3][t] = eluf(a3);
  }
  __syncthreads();
  {
    float bb = g1b[t];
    float a0 = bb, a1 = bb, a2 = bb, a3 = bb;
    for (int j = 0; j < 128; ++j) {
      float wv = g1w[j * 128 + t];
      a0 += h1[0][j] * wv; a1 += h1[1][j] * wv;
      a2 += h1[2][j] * wv; a3 += h1[3][j] * wv;
    }
    h2[0][t] = eluf(a0); h2[1][t] = eluf(a1);
    h2[2][t] = eluf(a2); h2[3][t] = eluf(a3);
  }
  __syncthreads();
  if (t < 32) {
    int r = t >> 3, e = t & 7;
    float a = g2b[e];
    for (int j = 0; j < 128; ++j) a += h2[r][j] * g2w[j * 8 + e];
    lg[r][e] = a;
  }
  __syncthreads();
  if (t < 32) {
    int r = t >> 3, e = t & 7;
    float mx = lg[r][0];
#pragma unroll
    for (int i = 1; i < 8; ++i) mx = fmaxf(mx, lg[r][i]);
    float s = 0.f;
#pragma unroll
    for (int i = 0; i < 8; ++i) s += __expf(lg[r][i] - mx);
    float p = __expf(lg[r][e] - mx) / s;
    coeff[(size_t)(r0 + r) * 8 + e] = p;
    pr[r][e] = p;
  }
  __syncthreads();
  if (t < 32) {
    int r = t >> 3, e = t & 7;
    float pe = pr[r][e];
    float ratio = (e < 7) ? pe / fmaxf(pr[r][e + 1], 1e-30f) : pe;
    rat2[(size_t)(r0 + r) * 8 + e] = (e == 3 || e == 7) ? pe : ratio;
    rat4[(size_t)(r0 + r) * 8 + e] = (e & 1) ? pe : ratio;
  }
}

// ---------------------------------------------------------------------------
// LayerNorm over concat([z_row, prev_row]) -> out [B][J] bf16.
//   p1 != null : prev = elu(p0 + p1 + sum_e cf[row,e]*bias[e,:])
//   p1 == null : prev = p0 raw (layer-0 path reading c)
// ---------------------------------------------------------------------------
__global__ __launch_bounds__(128) void ln_concat_k(
    const float* __restrict__ z, const float* __restrict__ p0,
    const float* __restrict__ p1, const float* __restrict__ cf,
    const float* __restrict__ bias, ushort_t* __restrict__ out,
    int Pw, int J) {
  int row = blockIdx.x, t = threadIdx.x;
  float vals[9];
  int n = (J + 127) >> 7;
  float cr[8];
  if (p1) {
#pragma unroll
    for (int e = 0; e < 8; ++e) cr[e] = cf[(size_t)row * 8 + e];
  }
  float s = 0.f, s2 = 0.f;
  for (int k = 0; k < n; ++k) {
    int i = t + (k << 7);
    float x = 0.f;
    if (i < J) {
      if (i < 64) {
        x = z[(size_t)row * 64 + i];
      } else if (p1) {
        int j = i - 64;
        float v = p0[(size_t)row * Pw + j] + p1[(size_t)row * Pw + j];
#pragma unroll
        for (int e = 0; e < 8; ++e) v += cr[e] * bias[(size_t)e * Pw + j];
        x = eluf(v);
      } else {
        x = p0[(size_t)row * Pw + i - 64];
      }
    }
    vals[k] = x; s += x; s2 += x * x;
  }
  for (int off = 32; off > 0; off >>= 1) {
    s += __shfl_down(s, off);
    s2 += __shfl_down(s2, off);
  }
  __shared__ float red[4];
  int wid = t >> 6, lane = t & 63;
  if (lane == 0) { red[wid * 2] = s; red[wid * 2 + 1] = s2; }
  __syncthreads();
  float S = red[0] + red[2], S2 = red[1] + red[3];
  float inv = 1.f / (float)J;
  float m = S * inv;
  float var = S2 * inv - m * m;
  float rstd = rsqrtf(var + 1e-5f);
  for (int k = 0; k < n; ++k) {
    int i = t + (k << 7);
    if (i < J) out[(size_t)row * J + i] = f2b((vals[k] - m) * rstd);
  }
}

// ---------------------------------------------------------------------------
// Fused MoE GEMM, round 11: per-phase DOUBLE-BARRIER lockstep (m201 schedule).
//
// Round-10 post-mortem: 4-phase interleave verified (+32%: 236->159.5us,
// MfmaUtil 40%). Cycle audit per K-tile: measured 5630 cyc vs MFMA floor
// 2480 + LDS floor ~1540-2050 — read/MFMA windows drift apart with only 2
// barriers per K-tile (waves' LDS and MFMA clusters overlap chaotically,
// both pipes idle alternately; LDS effective ~83 B/cyc). The m201 template's
// 62% comes from strict lockstep: EVERY phase brackets its 16-MFMA cluster
// with two raw barriers, so all 8 waves issue ds_reads in one tight
// full-rate window, then all MFMA. This round: same geometry/layout/vmcnt
// counting as round 10, but 8 barriers per K-tile:
//   ph0: {read Bk0+A m0-3 | stage A'(k0)} bar | 16 MFMA | bar
//   ph1: {read A m4-7     | stage W'(k0)} bar | 16 MFMA | vmcnt(4) bar
//   ph2: {read Bk1+A m0-3 | stage A'(k1)} bar | 16 MFMA | bar
//   ph3: {read A m4-7     | stage W'(k1)} bar | 16 MFMA | vmcnt(4) bar
// sched_barrier(0) pins MFMA clusters (rule 18: "memory" doesn't order
// register-only MFMA). vmcnt FIFO: each staged unit completes exactly one
// counted wait before first read (2 units slack).
//
// 512 thr / 8 waves (2M x 4N), per-wave 128x64, acc 8x4 f32x4.
// LDS: A 2buf x 2ks x 16KB + W same = 128KB + scales 9KB -> 1 block/CU.
// Grid 256 blocks = 1/CU via expert split (layers 0-2 ez=2, layer 3 ez=4).
// W offsets linear across experts; A col resets per expert. XCD = bt%8.
// ---------------------------------------------------------------------------
__device__ __forceinline__ void gload16(const void* g, void* l) {
  __builtin_amdgcn_global_load_lds(
      (const __attribute__((address_space(1))) void*)g,
      (__attribute__((address_space(3))) void*)l, 16, 0, 0);
}

#define BAR() asm volatile("s_barrier" ::: "memory")
#define VMC4() asm volatile("s_waitcnt vmcnt(4)" ::: "memory")
#define FENCE() __builtin_amdgcn_sched_barrier(0)

#define LOADB(Wb)                                                          \
  _Pragma("unroll") for (int fn = 0; fn < 4; ++fn) bf[fn] =                \
      *(const bf16x8*)((Wb) + (wn * 4 + fn) * 512 + l * 8);

#define LOADA(Ab, MB)                                                      \
  _Pragma("unroll") for (int q = 0; q < 4; ++q) af[q] =                    \
      *(const bf16x8*)((Ab) + (wm * 8 + (MB) + q) * 512 + l * 8);

#define DOMFMA(MB)                                                         \
  __builtin_amdgcn_s_setprio(1);                                           \
  _Pragma("unroll") for (int q = 0; q < 4; ++q)                            \
      _Pragma("unroll") for (int fn = 0; fn < 4; ++fn) acc[(MB) + q][fn] = \
          __builtin_amdgcn_mfma_f32_16x16x32_bf16(af[q], bf[fn],           \
                                                  acc[(MB) + q][fn], 0, 0, 0); \
  __builtin_amdgcn_s_setprio(0);

__global__ __launch_bounds__(512, 2) void moe_gemm_k(
    const ushort_t* __restrict__ inp,   // [B][J] bf16 (LN'd concat)
    const ushort_t* __restrict__ wT,    // [K][E*J] bf16 (pre-transposed)
    const float* __restrict__ scales,   // [B][8] Horner boundary scales
    float* __restrict__ outp,           // [nez][B][K] fp32 partials
    int J, int K, int ne) {
  const int Kd = E_EXP * J;
  const int nj = J >> 6;        // BK=64 tiles per expert
  const int nt = ne * nj;       // total K-tiles for this block's expert range
  __shared__ short As[2][2][16 * 512];   // [buf][ks][g*512 + l*8]  64KB
  __shared__ short Wsm[2][2][16 * 512];  // [buf][ks][h*512 + l*8]  64KB
  __shared__ float scale_s[256 * 9];     // [row][e] stride 9 (bank pad)

  const int t = threadIdx.x;
  const int w = t >> 6, l = t & 63;
  const int wm = w >> 2, wn = w & 3;     // 2M x 4N wave layout
  const int bt = blockIdx.x, ct = blockIdx.y, ez = blockIdx.z;
  const int e0 = ez * ne;
  outp += (size_t)ez * (size_t)B_ROWS * (size_t)K;

#pragma unroll
  for (int i = 0; i < 4; ++i) {
    int idx = t + (i << 9);  // 0..2047
    int rw = idx >> 3, e = idx & 7;
    scale_s[rw * 9 + e] = scales[(size_t)(bt * 256 + rw) * 8 + e];
  }

  // Stage bases: per wave 2 row-group blocks (1KB each) per 16KB unit.
  size_t abase[2], wbase[2];
#pragma unroll
  for (int i = 0; i < 2; ++i) {
    int g = w * 2 + i;
    abase[i] = (size_t)(bt * 256 + g * 16 + (l & 15)) * J + ((l >> 4) * 8);
    wbase[i] = (size_t)(ct * 256 + g * 16 + (l & 15)) * Kd + (size_t)e0 * J +
               ((l >> 4) * 8);
  }
  int s_acol = 0, s_wcol = 0, sjt = 0;  // stage-side counters (next tile)

  auto stageA = [&](int nb, int ks) {
    short* d = &As[nb][ks][w * 2 * 512];
    gload16(inp + abase[0] + s_acol + ks * 32, d);
    gload16(inp + abase[1] + s_acol + ks * 32, d + 512);
  };
  auto stageW = [&](int nb, int ks) {
    short* d = &Wsm[nb][ks][w * 2 * 512];
    gload16(wT + wbase[0] + s_wcol + ks * 32, d);
    gload16(wT + wbase[1] + s_wcol + ks * 32, d + 512);
  };
  auto advance = [&]() {
    s_wcol += 64;
    if (++sjt == nj) { sjt = 0; s_acol = 0; } else { s_acol += 64; }
  };

  f32x4 acc[8][4];
#pragma unroll
  for (int fm = 0; fm < 8; ++fm)
#pragma unroll
    for (int fn = 0; fn < 4; ++fn) acc[fm][fn] = (f32x4){0.f, 0.f, 0.f, 0.f};

  // prologue: tile 0 fully staged into buf 0; full drain once (also
  // publishes scale_s).
  stageA(0, 0); stageW(0, 0); stageA(0, 1); stageW(0, 1); advance();
  __syncthreads();

  int cjt = 0, cle = 0;  // compute-side counters
  for (int tp = 0; tp < nt; ++tp) {
    const int b = tp & 1, nb = b ^ 1;
    const bool more = (tp + 1 < nt);
    const short* A0 = &As[b][0][0];
    const short* A1 = &As[b][1][0];
    const short* W0 = &Wsm[b][0][0];
    const short* W1 = &Wsm[b][1][0];
    bf16x8 bf[4], af[4];

    // ---- phase 0: reads{B k0, A k0 m0-3} | stage A'(k0)
    LOADB(W0);
    LOADA(A0, 0);
    if (more) stageA(nb, 0);
    BAR(); FENCE();
    DOMFMA(0);
    FENCE();
    BAR();
    // ---- phase 1: reads{A k0 m4-7} | stage W'(k0)
    LOADA(A0, 4);
    if (more) stageW(nb, 0);
    BAR(); FENCE();
    DOMFMA(4);
    FENCE();
    VMC4();
    BAR();
    // ---- phase 2: reads{B k1, A k1 m0-3} | stage A'(k1)
    LOADB(W1);
    LOADA(A1, 0);
    if (more) stageA(nb, 1);
    BAR(); FENCE();
    DOMFMA(0);
    FENCE();
    BAR();
    // ---- phase 3: reads{A k1 m4-7} | stage W'(k1)
    LOADA(A1, 4);
    if (more) { stageW(nb, 1); advance(); }
    BAR(); FENCE();
    DOMFMA(4);
    FENCE();
    // Horner boundary rescale at expert end (1 of nj tiles)
    if (++cjt == nj) {
      cjt = 0;
      int e = e0 + cle;
      ++cle;
#pragma unroll
      for (int fi = 0; fi < 8; ++fi) {
        int rbase = wm * 128 + fi * 16 + ((l >> 4) << 2);
#pragma unroll
        for (int rr = 0; rr < 4; ++rr) {
          float rv = scale_s[(rbase + rr) * 9 + e];
#pragma unroll
          for (int fn = 0; fn < 4; ++fn) acc[fi][fn][rr] *= rv;
        }
      }
    }
    VMC4();
    BAR();
  }

  // epilogue: raw fp32 partial store (bias/ELU fused downstream)
#pragma unroll
  for (int fi = 0; fi < 8; ++fi) {
#pragma unroll
    for (int rr = 0; rr < 4; ++rr) {
      int row = wm * 128 + fi * 16 + ((l >> 4) << 2) + rr;
      size_t orow = (size_t)(bt * 256 + row) * K + ct * 256;
#pragma unroll
      for (int fn = 0; fn < 4; ++fn) {
        int col = wn * 64 + fn * 16 + (l & 15);
        outp[orow + col] = acc[fi][fn][rr];
      }
    }
  }
}

// ---------------------------------------------------------------------------
// Final combine for layer 3 (4-way expert split, K=512, no activation):
//   out = p0+p1+p2+p3 + coeff@bias
// ---------------------------------------------------------------------------
__global__ __launch_bounds__(256) void combine4_k(
    const float* __restrict__ pb, const float* __restrict__ cf,
    const float* __restrict__ bias, float* __restrict__ out, int K) {
  size_t i4 = (size_t)blockIdx.x * 256 + threadIdx.x;
  size_t total = (size_t)B_ROWS * (size_t)K;
  size_t base = i4 * 4;
  if (base >= total) return;
  int row = (int)(base / (size_t)K);
  int col = (int)(base % (size_t)K);
  size_t s4 = total >> 2;  // partial stride in f32x4 units
  const f32x4* p4 = (const f32x4*)pb;
  f32x4 v = p4[i4] + p4[i4 + s4] + p4[i4 + 2 * s4] + p4[i4 + 3 * s4];
#pragma unroll
  for (int e = 0; e < 8; ++e) {
    float ce = cf[(size_t)row * 8 + e];
    f32x4 bv = *(const f32x4*)(bias + (size_t)e * K + col);
    v += ce * bv;
  }
  ((f32x4*)out)[i4] = v;
}

// ---------------------------------------------------------------------------
extern "C" void kernel_launch(void* const* d_in, const int* in_sizes, int n_in,
                              void* d_out, int out_size, void* d_ws, size_t ws_size,
                              hipStream_t stream) {
  const float* z   = (const float*)d_in[0];
  const float* c   = (const float*)d_in[1];
  const float* g0w = (const float*)d_in[2];
  const float* g0b = (const float*)d_in[3];
  const float* g1w = (const float*)d_in[4];
  const float* g1b = (const float*)d_in[5];
  const float* g2w = (const float*)d_in[6];
  const float* g2b = (const float*)d_in[7];
  const float* w0  = (const float*)d_in[8];
  const float* b0  = (const float*)d_in[9];
  const float* w1  = (const float*)d_in[10];
  const float* b1  = (const float*)d_in[11];
  const float* w2  = (const float*)d_in[12];
  const float* b2  = (const float*)d_in[13];
  const float* w3  = (const float*)d_in[14];
  const float* b3  = (const float*)d_in[15];

  char* ws = (char*)d_ws;
  size_t o = 0;
  auto alloc = [&](size_t bytes) {
    void* p = ws + o;
    o += (bytes + 255) & ~(size_t)255;
    return p;
  };
  ushort_t* wT0 = (ushort_t*)alloc((size_t)2560 * 1024 * 2);
  ushort_t* wT1 = (ushort_t*)alloc((size_t)8704 * 1024 * 2);
  ushort_t* wT2 = (ushort_t*)alloc((size_t)8704 * 1024 * 2);
  ushort_t* wT3 = (ushort_t*)alloc((size_t)8704 * 512 * 2);
  float*    cf   = (float*)alloc((size_t)B_ROWS * 8 * 4);
  float*    rat2 = (float*)alloc((size_t)B_ROWS * 8 * 4);
  float*    rat4 = (float*)alloc((size_t)B_ROWS * 8 * 4);
  ushort_t* inp  = (ushort_t*)alloc((size_t)B_ROWS * 1088 * 2);
  float*    pb   = (float*)alloc((size_t)2 * B_ROWS * 1024 * 4);  // partials

  dim3 tb(64, 16);
  transpose_k<<<dim3(1024 / 64, 2560 / 64), tb, 0, stream>>>(w0, wT0, 2560, 1024);
  transpose_k<<<dim3(1024 / 64, 8704 / 64), tb, 0, stream>>>(w1, wT1, 8704, 1024);
  transpose_k<<<dim3(1024 / 64, 8704 / 64), tb, 0, stream>>>(w2, wT2, 8704, 1024);
  transpose_k<<<dim3(512 / 64, 8704 / 64), tb, 0, stream>>>(w3, wT3, 8704, 512);

  gate_k<<<B_ROWS / 4, 128, 0, stream>>>(z, c, g0w, g0b, g1w, g1b, g2w, g2b,
                                         cf, rat2, rat4);

  float* p1v = pb + (size_t)B_ROWS * 1024;

  // layer 0: J=320, K=1024, 2-way expert split (ne=4), grid 32x4x2 = 256
  ln_concat_k<<<B_ROWS, 128, 0, stream>>>(z, c, nullptr, nullptr, nullptr,
                                          inp, 256, 320);
  moe_gemm_k<<<dim3(32, 4, 2), 512, 0, stream>>>(inp, wT0, rat2, pb, 320, 1024, 4);
  // layer 1: J=1088, K=1024 (ln fuses partial combine + b0-mix + elu)
  ln_concat_k<<<B_ROWS, 128, 0, stream>>>(z, pb, p1v, cf, b0, inp, 1024, 1088);
  moe_gemm_k<<<dim3(32, 4, 2), 512, 0, stream>>>(inp, wT1, rat2, pb, 1088, 1024, 4);
  // layer 2
  ln_concat_k<<<B_ROWS, 128, 0, stream>>>(z, pb, p1v, cf, b1, inp, 1024, 1088);
  moe_gemm_k<<<dim3(32, 4, 2), 512, 0, stream>>>(inp, wT2, rat2, pb, 1088, 1024, 4);
  // layer 3: J=1088, K=512, 4-way expert split (ne=2), grid 32x2x4 = 256
  ln_concat_k<<<B_ROWS, 128, 0, stream>>>(z, pb, p1v, cf, b2, inp, 1024, 1088);
  moe_gemm_k<<<dim3(32, 2, 4), 512, 0, stream>>>(inp, wT3, rat4, pb, 1088, 512, 2);
  combine4_k<<<(B_ROWS * 512) / 1024, 256, 0, stream>>>(pb, cf, b3,
                                                        (float*)d_out, 512);
}